// Round 1
// baseline (214.319 us; speedup 1.0000x reference)
//
#include <hip/hip_runtime.h>
#include <hip/hip_bf16.h>
#include <stdint.h>

// Problem constants
#define SEQL   2048
#define NBATCH 2
#define BSZ    4096   // NBATCH*SEQL
#define DMODEL 1024
#define NH     16
#define DK     64
#define NBH    32     // NBATCH*NH

typedef __attribute__((ext_vector_type(8))) short short8;
typedef __attribute__((ext_vector_type(4))) short shortx4;
typedef __attribute__((ext_vector_type(4))) float f32x4;

__device__ __forceinline__ short f2b(float f) {   // f32 -> bf16 (RNE)
  unsigned u = __float_as_uint(f);
  u = (u + 0x7FFF + ((u >> 16) & 1)) >> 16;
  return (short)u;
}
__device__ __forceinline__ float b2f(short s) {
  return __uint_as_float(((unsigned)(unsigned short)s) << 16);
}

// async global->LDS, 16B per lane. LDS dest = wave-uniform base + lane*16.
__device__ __forceinline__ void g2l16(const void* g, void* l) {
  __builtin_amdgcn_global_load_lds(
      (__attribute__((address_space(1))) void*)(uintptr_t)g,
      (__attribute__((address_space(3))) void*)l, 16, 0, 0);
}

__device__ __forceinline__ f32x4 mfma16(short8 a, short8 b, f32x4 c) {
  return __builtin_amdgcn_mfma_f32_16x16x32_bf16(a, b, c, 0, 0, 0);
}

// ---------------------------------------------------------------- cvt f32->bf16
// regions: x (4M) -> xb ; Wq,Wk,Wv (1M each) -> wqkv ; Wo (1M) -> wob
__global__ void cvt_all(const float* __restrict__ x,  const float* __restrict__ wq,
                        const float* __restrict__ wk, const float* __restrict__ wv,
                        const float* __restrict__ wo, short* __restrict__ xb,
                        short* __restrict__ wqkv, short* __restrict__ wob) {
  long idx = ((long)blockIdx.x * 256 + threadIdx.x) * 4;
  const float* s; short* d; long off;
  if (idx < 4194304L)      { s = x;  d = xb;             off = idx; }
  else if (idx < 5242880L) { s = wq; d = wqkv;           off = idx - 4194304L; }
  else if (idx < 6291456L) { s = wk; d = wqkv + 1048576; off = idx - 5242880L; }
  else if (idx < 7340032L) { s = wv; d = wqkv + 2097152; off = idx - 6291456L; }
  else                     { s = wo; d = wob;            off = idx - 7340032L; }
  float4 v = *(const float4*)(s + off);
  shortx4 r;
  r[0] = f2b(v.x); r[1] = f2b(v.y); r[2] = f2b(v.z); r[3] = f2b(v.w);
  *(shortx4*)(d + off) = r;
}

// ---------------------------------------------------------------- GEMM  C = A * B^T
// A[M][K], B[N][K] row-major bf16; C row-major (bf16 if CBF16 else f32).
// 128x128 tile, BK=32, 4 waves in 2x2, each wave 64x64 = 4x4 frags of 16x16x32.
// LDS 16B-chunk XOR swizzle key = (row>>1)&3 (conflict-free within lane octets).
template<int CBF16>
__global__ __launch_bounds__(256, 2)
void gemm_bt(const short* __restrict__ A, const short* __restrict__ B,
             void* __restrict__ Cv, int M, int N, int K,
             long bStride, long cStride) {
  __shared__ short As[4096];
  __shared__ short Bs[4096];
  B += (long)blockIdx.y * bStride;
  int nbn = N >> 7;
  int bm = blockIdx.x / nbn, bn = blockIdx.x % nbn;
  int tid = threadIdx.x, w = tid >> 6, l = tid & 63;
  int wm = w >> 1, wn = w & 1;
  int lr = l & 15, lg = l >> 4;
  int brow = bm << 7, bcol = bn << 7;

  const f32x4 fz = {0.f, 0.f, 0.f, 0.f};
  f32x4 acc[4][4];
#pragma unroll
  for (int xi = 0; xi < 4; ++xi) {
#pragma unroll
    for (int yi = 0; yi < 4; ++yi) acc[xi][yi] = fz;
  }

  for (int k0 = 0; k0 < K; k0 += 32) {
    // stage A,B tiles: 512 chunks of 8 elems each; chunk = row*4+ch, pre-swizzled src
#pragma unroll
    for (int i = 0; i < 2; ++i) {
      int c = w * 2 + i;
      int chunk = c * 64 + l;
      int row = chunk >> 2, ch = chunk & 3;
      int gch = ch ^ ((row >> 1) & 3);
      g2l16(A + (long)(brow + row) * K + k0 + gch * 8, &As[c * 512]);
      g2l16(B + (long)(bcol + row) * K + k0 + gch * 8, &Bs[c * 512]);
    }
    __syncthreads();

    short8 af[4], bf[4];
#pragma unroll
    for (int xi = 0; xi < 4; ++xi) {
      int ar = wm * 64 + xi * 16 + lr;
      af[xi] = *(const short8*)&As[ar * 32 + ((lg ^ ((ar >> 1) & 3)) << 3)];
      int br = wn * 64 + xi * 16 + lr;
      bf[xi] = *(const short8*)&Bs[br * 32 + ((lg ^ ((br >> 1) & 3)) << 3)];
    }
#pragma unroll
    for (int xi = 0; xi < 4; ++xi) {
#pragma unroll
      for (int yi = 0; yi < 4; ++yi)
        acc[xi][yi] = mfma16(af[xi], bf[yi], acc[xi][yi]);
    }
    __syncthreads();
  }

  // epilogue: C/D layout col=lane&15, row=(lane>>4)*4+reg
  if (CBF16) {
    short* C = (short*)Cv + (long)blockIdx.y * cStride;
#pragma unroll
    for (int xi = 0; xi < 4; ++xi) {
#pragma unroll
      for (int yi = 0; yi < 4; ++yi) {
#pragma unroll
        for (int r = 0; r < 4; ++r) {
          int row = brow + wm * 64 + xi * 16 + lg * 4 + r;
          int col = bcol + wn * 64 + yi * 16 + lr;
          C[(long)row * N + col] = f2b(acc[xi][yi][r]);
        }
      }
    }
  } else {
    float* C = (float*)Cv;
#pragma unroll
    for (int xi = 0; xi < 4; ++xi) {
#pragma unroll
      for (int yi = 0; yi < 4; ++yi) {
#pragma unroll
        for (int r = 0; r < 4; ++r) {
          int row = brow + wm * 64 + xi * 16 + lg * 4 + r;
          int col = bcol + wn * 64 + yi * 16 + lr;
          C[(long)row * N + col] = acc[xi][yi][r];
        }
      }
    }
  }
}

// ---------------------------------------------------------------- RoPE + head split
// qkv: Q at +0, K at +4M, both [BSZ][1024] bf16. Writes Qh,Kh [b][h][s][64] bf16.
// Q gets *0.125 (1/sqrt(DK), exact in bf16).
__global__ void rope_split(const short* __restrict__ qkv, const int* __restrict__ tok,
                           short* __restrict__ Qh, short* __restrict__ Kh) {
  int t = blockIdx.x * 256 + threadIdx.x;       // [0, BSZ*NH*16)
  int qd = t & 15, h = (t >> 4) & 15, bs = t >> 8;
  int b = bs >> 11, s = bs & 2047;
  float pos = (float)tok[s];
  long srcoff = (long)bs * 1024 + h * 64 + qd * 4;
  shortx4 q4 = *(const shortx4*)(qkv + srcoff);
  shortx4 k4 = *(const shortx4*)(qkv + 4194304L + srcoff);
  shortx4 qo, ko;
#pragma unroll
  for (int p = 0; p < 2; ++p) {
    int i = qd * 2 + p;                          // pair index 0..31
    float freq = exp2f(-(float)i * (13.287712379549449f / 32.0f)); // theta^(-2i/64)
    float ang = pos * freq;
    float sn, cs;
    sincosf(ang, &sn, &cs);
    float x1 = b2f(q4[p * 2]), x2 = b2f(q4[p * 2 + 1]);
    qo[p * 2]     = f2b((x1 * cs - x2 * sn) * 0.125f);
    qo[p * 2 + 1] = f2b((x1 * sn + x2 * cs) * 0.125f);
    float y1 = b2f(k4[p * 2]), y2 = b2f(k4[p * 2 + 1]);
    ko[p * 2]     = f2b(y1 * cs - y2 * sn);
    ko[p * 2 + 1] = f2b(y1 * sn + y2 * cs);
  }
  long outoff = ((long)(b * 16 + h) * 2048 + s) * 64 + qd * 4;
  *(shortx4*)(Qh + outoff) = qo;
  *(shortx4*)(Kh + outoff) = ko;
}

// ---------------------------------------------------------------- V transpose
// Vlin [BSZ][1024] (head h cols) -> Vt [bh][64 d][2048 s]
__global__ void vtrans(const short* __restrict__ Vlin, short* __restrict__ Vt) {
  __shared__ short tile[64][72];               // +8 pad breaks bank collisions
  int s0 = blockIdx.x * 64;
  int bh = blockIdx.y;
  int b = bh >> 4, h = bh & 15;
  int t = threadIdx.x;
  int r = t >> 2, c0 = (t & 3) * 16;
  const short* src = Vlin + ((long)(b * 2048 + s0 + r)) * 1024 + h * 64 + c0;
  *(short8*)&tile[r][c0]     = *(const short8*)src;
  *(short8*)&tile[r][c0 + 8] = *(const short8*)(src + 8);
  __syncthreads();
  int d = t >> 2, sc0 = (t & 3) * 16;
  short8 o0, o1;
#pragma unroll
  for (int j = 0; j < 8; ++j) { o0[j] = tile[sc0 + j][d]; o1[j] = tile[sc0 + 8 + j][d]; }
  short* dst = Vt + ((long)(bh * 64 + d)) * 2048 + s0 + sc0;
  *(short8*)dst       = o0;
  *(short8*)(dst + 8) = o1;
}

// ---------------------------------------------------------------- causal flash attention
// grid (S/64, NBH), 4 waves; wave w owns q-rows q0+16w..+15. KVBLK=64.
// K LDS [kv][64], Vt LDS [d][64kv], both ^(row&7) 16B-chunk swizzled.
__global__ __launch_bounds__(256, 2)
void attn_fwd(const short* __restrict__ Qh, const short* __restrict__ Kh,
              const short* __restrict__ Vt, short* __restrict__ Oh) {
  __shared__ short Ks[4096];
  __shared__ short Vs[4096];
  __shared__ short Ps[4][1024];                 // per-wave P buffer [16][64]
  int q0 = blockIdx.x * 64;
  int bh = blockIdx.y;
  int b = bh >> 4, h = bh & 15;
  int tid = threadIdx.x, w = tid >> 6, l = tid & 63;
  int lr = l & 15, lg = l >> 4;
  const short* Qb = Qh + (long)bh * (2048 * 64);
  const short* Kb = Kh + (long)bh * (2048 * 64);
  const short* Vb = Vt + (long)bh * (64 * 2048);

  int qrow = q0 + w * 16 + lr;
  short8 qa0 = *(const short8*)(Qb + (long)qrow * 64 + lg * 8);
  short8 qa1 = *(const short8*)(Qb + (long)qrow * 64 + 32 + lg * 8);

  const f32x4 fz = {0.f, 0.f, 0.f, 0.f};
  f32x4 o[4];
#pragma unroll
  for (int n = 0; n < 4; ++n) o[n] = fz;
  f32x4 mrow = {-1e30f, -1e30f, -1e30f, -1e30f};
  f32x4 lsum = fz;

  int ntiles = (q0 >> 6) + 1;
  for (int tile = 0; tile < ntiles; ++tile) {
    int s0 = tile << 6;
    // stage K and Vt tiles (8KB each): 512 chunks, row=chunk>>3, pre-swizzled src
#pragma unroll
    for (int i = 0; i < 2; ++i) {
      int c = w * 2 + i;
      int chunk = c * 64 + l;
      int row = chunk >> 3, ch = chunk & 7;
      int gch = ch ^ (row & 7);
      g2l16(Kb + (long)(s0 + row) * 64 + gch * 8, &Ks[c * 512]);
      g2l16(Vb + (long)row * 2048 + s0 + gch * 8, &Vs[c * 512]);
    }
    __syncthreads();

    // S = Q K^T (pre-scaled by 1/8 via Q)
    f32x4 sc[4];
#pragma unroll
    for (int n = 0; n < 4; ++n) sc[n] = fz;
#pragma unroll
    for (int n = 0; n < 4; ++n) {
      int kr = n * 16 + lr, rb = kr & 7;
      short8 kb0 = *(const short8*)&Ks[kr * 64 + ((lg ^ rb) << 3)];
      short8 kb1 = *(const short8*)&Ks[kr * 64 + (((4 + lg) ^ rb) << 3)];
      sc[n] = mfma16(qa0, kb0, sc[n]);
      sc[n] = mfma16(qa1, kb1, sc[n]);
    }
    // causal mask (only the diagonal tile needs it: s0 == q0 there)
    if (tile == ntiles - 1) {
#pragma unroll
      for (int n = 0; n < 4; ++n) {
#pragma unroll
        for (int r = 0; r < 4; ++r) {
          int col = s0 + n * 16 + lr;
          int rowg = q0 + w * 16 + lg * 4 + r;
          if (col > rowg) sc[n][r] = -1e30f;
        }
      }
    }
    // row-max (cols live across 16 lanes of same group + 4 frags)
    f32x4 pm = sc[0];
#pragma unroll
    for (int n = 1; n < 4; ++n) {
#pragma unroll
      for (int r = 0; r < 4; ++r) pm[r] = fmaxf(pm[r], sc[n][r]);
    }
#pragma unroll
    for (int off = 1; off < 16; off <<= 1) {
#pragma unroll
      for (int r = 0; r < 4; ++r) pm[r] = fmaxf(pm[r], __shfl_xor(pm[r], off));
    }
    f32x4 mn, sf;
#pragma unroll
    for (int r = 0; r < 4; ++r) {
      mn[r] = fmaxf(mrow[r], pm[r]);
      sf[r] = exp2f((mrow[r] - mn[r]) * 1.44269504f);
      mrow[r] = mn[r];
    }
    f32x4 rs = fz;
#pragma unroll
    for (int n = 0; n < 4; ++n) {
#pragma unroll
      for (int r = 0; r < 4; ++r) {
        float p = exp2f((sc[n][r] - mn[r]) * 1.44269504f);
        sc[n][r] = p;
        rs[r] += p;
      }
    }
#pragma unroll
    for (int off = 1; off < 16; off <<= 1) {
#pragma unroll
      for (int r = 0; r < 4; ++r) rs[r] += __shfl_xor(rs[r], off);
    }
#pragma unroll
    for (int r = 0; r < 4; ++r) lsum[r] = lsum[r] * sf[r] + rs[r];
#pragma unroll
    for (int n = 0; n < 4; ++n) {
#pragma unroll
      for (int r = 0; r < 4; ++r) o[n][r] *= sf[r];
    }
    // P (C-layout) -> per-wave LDS, swizzled, as bf16
#pragma unroll
    for (int n = 0; n < 4; ++n) {
#pragma unroll
      for (int r = 0; r < 4; ++r) {
        int prow = lg * 4 + r, pcol = n * 16 + lr;
        Ps[w][prow * 64 + ((((pcol >> 3) ^ (prow & 7))) << 3) + (pcol & 7)] =
            f2b(sc[n][r]);
      }
    }
    asm volatile("s_waitcnt lgkmcnt(0)" ::: "memory");
    __builtin_amdgcn_sched_barrier(0);
    // PV: A = P (A-layout read from LDS), B = Vt
    int pb = lr & 7;
    short8 pa0 = *(const short8*)&Ps[w][lr * 64 + ((lg ^ pb) << 3)];
    short8 pa1 = *(const short8*)&Ps[w][lr * 64 + (((4 + lg) ^ pb) << 3)];
#pragma unroll
    for (int n = 0; n < 4; ++n) {
      int vr = n * 16 + lr, rb = vr & 7;
      short8 vb0 = *(const short8*)&Vs[vr * 64 + ((lg ^ rb) << 3)];
      short8 vb1 = *(const short8*)&Vs[vr * 64 + (((4 + lg) ^ rb) << 3)];
      o[n] = mfma16(pa0, vb0, o[n]);
      o[n] = mfma16(pa1, vb1, o[n]);
    }
    __syncthreads();
  }

  f32x4 inv;
#pragma unroll
  for (int r = 0; r < 4; ++r) inv[r] = 1.0f / lsum[r];
#pragma unroll
  for (int n = 0; n < 4; ++n) {
#pragma unroll
    for (int r = 0; r < 4; ++r) {
      int rowg = q0 + w * 16 + lg * 4 + r;
      int col = h * 64 + n * 16 + lr;
      Oh[((long)(b * 2048 + rowg)) * 1024 + col] = f2b(o[n][r] * inv[r]);
    }
  }
}

// ---------------------------------------------------------------- launch
extern "C" void kernel_launch(void* const* d_in, const int* in_sizes, int n_in,
                              void* d_out, int out_size, void* d_ws, size_t ws_size,
                              hipStream_t stream) {
  const float* x  = (const float*)d_in[0];
  const float* wq = (const float*)d_in[1];
  const float* wk = (const float*)d_in[2];
  const float* wv = (const float*)d_in[3];
  const float* wo = (const float*)d_in[4];
  const int* tok  = (const int*)d_in[5];

  short* wsp  = (short*)d_ws;
  short* xb   = wsp;                    //  4M shorts
  short* wqkv = xb + 4194304;           //  3M
  short* wob  = wqkv + 3145728;         //  1M
  short* qkv  = wob + 1048576;          // 12M (Q | K | V, 4M each)
  short* qh   = qkv + 12582912;         //  4M
  short* kh   = qh + 4194304;           //  4M
  short* vt   = kh + 4194304;           //  4M
  short* oh   = vt + 4194304;           //  4M   total 36M shorts = 72MB

  (void)in_sizes; (void)n_in; (void)out_size; (void)ws_size;

  cvt_all<<<8192, 256, 0, stream>>>(x, wq, wk, wv, wo, xb, wqkv, wob);
  // Q,K,V projections in one launch (grid.y selects weight/output)
  gemm_bt<1><<<dim3(256, 3), 256, 0, stream>>>(xb, wqkv, qkv, 4096, 1024, 1024,
                                               1048576L, 4194304L);
  rope_split<<<4096, 256, 0, stream>>>(qkv, tok, qh, kh);
  vtrans<<<dim3(32, 32), 256, 0, stream>>>(qkv + 8388608, vt);
  attn_fwd<<<dim3(32, 32), 256, 0, stream>>>(qh, kh, vt, oh);
  gemm_bt<0><<<dim3(256, 1), 256, 0, stream>>>(oh, wob, d_out, 4096, 1024, 1024,
                                               0L, 0L);
}

// Round 2
// 156.707 us; speedup vs baseline: 1.3676x; 1.3676x over previous
//
#include <hip/hip_runtime.h>
#include <hip/hip_bf16.h>
#include <stdint.h>

// Problem constants
#define SEQL   2048
#define NBATCH 2
#define BSZ    4096   // NBATCH*SEQL
#define DMODEL 1024
#define NH     16
#define DK     64
#define NBH    32     // NBATCH*NH

typedef __attribute__((ext_vector_type(8)))  short short8;
typedef __attribute__((ext_vector_type(4)))  short shortx4;
typedef __attribute__((ext_vector_type(4)))  float f32x4;
typedef __attribute__((ext_vector_type(16))) float f32x16;
typedef __attribute__((ext_vector_type(4)))  unsigned uint4v;
union PU { uint4v u; short8 s; };

__device__ __forceinline__ short f2b(float f) {   // f32 -> bf16 (RNE)
  unsigned u = __float_as_uint(f);
  u = (u + 0x7FFF + ((u >> 16) & 1)) >> 16;
  return (short)u;
}
__device__ __forceinline__ float b2f(short s) {
  return __uint_as_float(((unsigned)(unsigned short)s) << 16);
}
__device__ __forceinline__ unsigned cvtpk(float lo, float hi) {
  unsigned r;
  asm("v_cvt_pk_bf16_f32 %0, %1, %2" : "=v"(r) : "v"(lo), "v"(hi));
  return r;
}

// async global->LDS, 16B per lane. LDS dest = wave-uniform base + lane*16.
__device__ __forceinline__ void g2l16(const void* g, void* l) {
  __builtin_amdgcn_global_load_lds(
      (__attribute__((address_space(1))) void*)(uintptr_t)g,
      (__attribute__((address_space(3))) void*)l, 16, 0, 0);
}

__device__ __forceinline__ f32x4 mfma16(short8 a, short8 b, f32x4 c) {
  return __builtin_amdgcn_mfma_f32_16x16x32_bf16(a, b, c, 0, 0, 0);
}
__device__ __forceinline__ f32x16 mfma32(short8 a, short8 b, f32x16 c) {
  return __builtin_amdgcn_mfma_f32_32x32x16_bf16(a, b, c, 0, 0, 0);
}

// ---------------------------------------------------------------- cvt f32->bf16
__global__ void cvt_all(const float* __restrict__ x,  const float* __restrict__ wq,
                        const float* __restrict__ wk, const float* __restrict__ wv,
                        const float* __restrict__ wo, short* __restrict__ xb,
                        short* __restrict__ wqkv, short* __restrict__ wob) {
  long idx = ((long)blockIdx.x * 256 + threadIdx.x) * 4;
  const float* s; short* d; long off;
  if (idx < 4194304L)      { s = x;  d = xb;             off = idx; }
  else if (idx < 5242880L) { s = wq; d = wqkv;           off = idx - 4194304L; }
  else if (idx < 6291456L) { s = wk; d = wqkv + 1048576; off = idx - 5242880L; }
  else if (idx < 7340032L) { s = wv; d = wqkv + 2097152; off = idx - 6291456L; }
  else                     { s = wo; d = wob;            off = idx - 7340032L; }
  float4 v = *(const float4*)(s + off);
  shortx4 r;
  r[0] = f2b(v.x); r[1] = f2b(v.y); r[2] = f2b(v.z); r[3] = f2b(v.w);
  *(shortx4*)(d + off) = r;
}

// ---------------------------------------------------------------- GEMM  C = A * B^T
template<int CBF16>
__global__ __launch_bounds__(256, 2)
void gemm_bt(const short* __restrict__ A, const short* __restrict__ B,
             void* __restrict__ Cv, int M, int N, int K,
             long bStride, long cStride) {
  __shared__ short As[4096];
  __shared__ short Bs[4096];
  B += (long)blockIdx.y * bStride;
  int nbn = N >> 7;
  int bm = blockIdx.x / nbn, bn = blockIdx.x % nbn;
  int tid = threadIdx.x, w = tid >> 6, l = tid & 63;
  int wm = w >> 1, wn = w & 1;
  int lr = l & 15, lg = l >> 4;
  int brow = bm << 7, bcol = bn << 7;

  const f32x4 fz = {0.f, 0.f, 0.f, 0.f};
  f32x4 acc[4][4];
#pragma unroll
  for (int xi = 0; xi < 4; ++xi)
#pragma unroll
    for (int yi = 0; yi < 4; ++yi) acc[xi][yi] = fz;

  for (int k0 = 0; k0 < K; k0 += 32) {
#pragma unroll
    for (int i = 0; i < 2; ++i) {
      int c = w * 2 + i;
      int chunk = c * 64 + l;
      int row = chunk >> 2, ch = chunk & 3;
      int gch = ch ^ ((row >> 1) & 3);
      g2l16(A + (long)(brow + row) * K + k0 + gch * 8, &As[c * 512]);
      g2l16(B + (long)(bcol + row) * K + k0 + gch * 8, &Bs[c * 512]);
    }
    __syncthreads();

    short8 af[4], bf[4];
#pragma unroll
    for (int xi = 0; xi < 4; ++xi) {
      int ar = wm * 64 + xi * 16 + lr;
      af[xi] = *(const short8*)&As[ar * 32 + ((lg ^ ((ar >> 1) & 3)) << 3)];
      int br = wn * 64 + xi * 16 + lr;
      bf[xi] = *(const short8*)&Bs[br * 32 + ((lg ^ ((br >> 1) & 3)) << 3)];
    }
#pragma unroll
    for (int xi = 0; xi < 4; ++xi)
#pragma unroll
      for (int yi = 0; yi < 4; ++yi)
        acc[xi][yi] = mfma16(af[xi], bf[yi], acc[xi][yi]);
    __syncthreads();
  }

  if (CBF16) {
    short* C = (short*)Cv + (long)blockIdx.y * cStride;
#pragma unroll
    for (int xi = 0; xi < 4; ++xi)
#pragma unroll
      for (int yi = 0; yi < 4; ++yi)
#pragma unroll
        for (int r = 0; r < 4; ++r) {
          int row = brow + wm * 64 + xi * 16 + lg * 4 + r;
          int col = bcol + wn * 64 + yi * 16 + lr;
          C[(long)row * N + col] = f2b(acc[xi][yi][r]);
        }
  } else {
    float* C = (float*)Cv;
#pragma unroll
    for (int xi = 0; xi < 4; ++xi)
#pragma unroll
      for (int yi = 0; yi < 4; ++yi)
#pragma unroll
        for (int r = 0; r < 4; ++r) {
          int row = brow + wm * 64 + xi * 16 + lg * 4 + r;
          int col = bcol + wn * 64 + yi * 16 + lr;
          C[(long)row * N + col] = acc[xi][yi][r];
        }
  }
}

// ---------------------------------------------------------------- RoPE + head split
__global__ void rope_split(const short* __restrict__ qkv, const int* __restrict__ tok,
                           short* __restrict__ Qh, short* __restrict__ Kh) {
  int t = blockIdx.x * 256 + threadIdx.x;
  int qd = t & 15, h = (t >> 4) & 15, bs = t >> 8;
  int b = bs >> 11, s = bs & 2047;
  float pos = (float)tok[s];
  long srcoff = (long)bs * 1024 + h * 64 + qd * 4;
  shortx4 q4 = *(const shortx4*)(qkv + srcoff);
  shortx4 k4 = *(const shortx4*)(qkv + 4194304L + srcoff);
  shortx4 qo, ko;
#pragma unroll
  for (int p = 0; p < 2; ++p) {
    int i = qd * 2 + p;
    float freq = exp2f(-(float)i * (13.287712379549449f / 32.0f));
    float ang = pos * freq;
    float sn, cs;
    sincosf(ang, &sn, &cs);
    float x1 = b2f(q4[p * 2]), x2 = b2f(q4[p * 2 + 1]);
    qo[p * 2]     = f2b((x1 * cs - x2 * sn) * 0.125f);
    qo[p * 2 + 1] = f2b((x1 * sn + x2 * cs) * 0.125f);
    float y1 = b2f(k4[p * 2]), y2 = b2f(k4[p * 2 + 1]);
    ko[p * 2]     = f2b(y1 * cs - y2 * sn);
    ko[p * 2 + 1] = f2b(y1 * sn + y2 * cs);
  }
  long outoff = ((long)(b * 16 + h) * 2048 + s) * 64 + qd * 4;
  *(shortx4*)(Qh + outoff) = qo;
  *(shortx4*)(Kh + outoff) = ko;
}

// ---------------------------------------------------------------- V transpose
__global__ void vtrans(const short* __restrict__ Vlin, short* __restrict__ Vt) {
  __shared__ short tile[64][72];
  int s0 = blockIdx.x * 64;
  int bh = blockIdx.y;
  int b = bh >> 4, h = bh & 15;
  int t = threadIdx.x;
  int r = t >> 2, c0 = (t & 3) * 16;
  const short* src = Vlin + ((long)(b * 2048 + s0 + r)) * 1024 + h * 64 + c0;
  *(short8*)&tile[r][c0]     = *(const short8*)src;
  *(short8*)&tile[r][c0 + 8] = *(const short8*)(src + 8);
  __syncthreads();
  int d = t >> 2, sc0 = (t & 3) * 16;
  short8 o0, o1;
#pragma unroll
  for (int j = 0; j < 8; ++j) { o0[j] = tile[sc0 + j][d]; o1[j] = tile[sc0 + 8 + j][d]; }
  short* dst = Vt + ((long)(bh * 64 + d)) * 2048 + s0 + sc0;
  *(short8*)dst       = o0;
  *(short8*)(dst + 8) = o1;
}

// ---------------------------------------------------------------- causal flash attention
// Swapped QK^T, 32x32x16 MFMA. grid (16, NBH), 4 waves x 32 q-rows = 128 q/block.
// KVBLK=64. K,Vt staged in fragment order (lane l <-> offset l*16B): linear
// ds_read_b128, conflict-free, matches global_load_lds linear dest.
// 2-phase pipeline: raw s_barrier + counted vmcnt(4).
__global__ __launch_bounds__(256, 2)
void attn_fwd(const short* __restrict__ Qh, const short* __restrict__ Kh,
              const short* __restrict__ Vt, short* __restrict__ Oh) {
  __shared__ short Ks[2][4096];
  __shared__ short Vs[2][4096];
  int qi = 15 - blockIdx.x;                    // heavy-first dispatch
  int q0b = qi << 7;
  int bh = blockIdx.y;
  int b = bh >> 4, h = bh & 15;
  int tid = threadIdx.x, w = tid >> 6, l = tid & 63;
  int ql = l & 31, hi = l >> 5;
  const short* Qb = Qh + (long)bh * (2048 * 64);
  const short* Kb = Kh + (long)bh * (2048 * 64);
  const short* Vb = Vt + (long)bh * (64 * 2048);
  int qw = q0b + 32 * w;
  int qg = qw + ql;

  // Q B-fragments: lane l holds Q[qw+ql][kc*16 + hi*8 + 0..8)
  short8 qf[4];
#pragma unroll
  for (int kc = 0; kc < 4; ++kc)
    qf[kc] = *(const short8*)(Qb + (long)qg * 64 + kc * 16 + hi * 8);

  f32x16 o0, o1;
#pragma unroll
  for (int r = 0; r < 16; ++r) { o0[r] = 0.f; o1[r] = 0.f; }
  float m = -1e30f, lsum = 0.f;

  int nt = (q0b >> 6) + 2;

#define STAGE(t_, bufi_) do {                                                   \
    int s0_ = (t_) << 6;                                                        \
    _Pragma("unroll")                                                           \
    for (int i_ = 0; i_ < 2; ++i_) {                                            \
      int c_ = w + 4 * i_;                                                      \
      int g_ = c_ >> 2, cc_ = c_ & 3;                                           \
      g2l16(Kb + ((long)(s0_ + g_ * 32 + ql)) * 64 + cc_ * 16 + hi * 8,         \
            &Ks[bufi_][c_ * 512]);                                              \
      g2l16(Vb + ((long)(g_ * 32 + ql)) * 2048 + s0_ + cc_ * 16 + hi * 8,       \
            &Vs[bufi_][c_ * 512]);                                              \
    }                                                                           \
  } while (0)

  STAGE(0, 0);

  for (int t = 0; t < nt; ++t) {
    int cur = t & 1;
    if (t + 1 < nt) {
      STAGE(t + 1, cur ^ 1);
      asm volatile("s_waitcnt vmcnt(4)" ::: "memory");
    } else {
      asm volatile("s_waitcnt vmcnt(0)" ::: "memory");
    }
    __builtin_amdgcn_s_barrier();
    int s0 = t << 6;
    if (s0 <= qw + 31) {
      // ---- QK^T (swapped): sT[kv][q], lane owns q-col = ql
      f32x16 sT0, sT1;
#pragma unroll
      for (int r = 0; r < 16; ++r) { sT0[r] = 0.f; sT1[r] = 0.f; }
      __builtin_amdgcn_s_setprio(1);
#pragma unroll
      for (int kc = 0; kc < 4; ++kc) {
        short8 k0 = *(const short8*)&Ks[cur][(kc * 64 + l) * 8];
        short8 k1 = *(const short8*)&Ks[cur][((4 + kc) * 64 + l) * 8];
        sT0 = mfma32(k0, qf[kc], sT0);
        sT1 = mfma32(k1, qf[kc], sT1);
      }
      __builtin_amdgcn_s_setprio(0);
      // ---- causal mask
      if (s0 + 63 > qw) {
#pragma unroll
        for (int r = 0; r < 16; ++r) {
          int kvl = (r & 3) + 8 * (r >> 2) + 4 * hi;
          if (s0 + kvl > qg)      sT0[r] = -1e30f;
          if (s0 + 32 + kvl > qg) sT1[r] = -1e30f;
        }
      }
      // ---- online softmax (row = lane-local + partner via shfl_xor 32)
      float pmax = sT0[0];
#pragma unroll
      for (int r = 1; r < 16; ++r) pmax = fmaxf(pmax, sT0[r]);
#pragma unroll
      for (int r = 0; r < 16; ++r) pmax = fmaxf(pmax, sT1[r]);
      pmax = fmaxf(pmax, __shfl_xor(pmax, 32));
      if (__any(pmax > m + 8.0f)) {            // T13 defer-max
        float mn = fmaxf(m, pmax);
        float sf = exp2f((m - mn) * 1.44269504f);
        m = mn;
        lsum *= sf;
#pragma unroll
        for (int r = 0; r < 16; ++r) {
          int row = (r & 3) + 8 * (r >> 2) + 4 * hi;
          float fo = __shfl(sf, row);
          o0[r] *= fo; o1[r] *= fo;
        }
      }
      float rs = 0.f;
#pragma unroll
      for (int r = 0; r < 16; ++r) {
        float p = exp2f((sT0[r] - m) * 1.44269504f);
        sT0[r] = p; rs += p;
      }
#pragma unroll
      for (int r = 0; r < 16; ++r) {
        float p = exp2f((sT1[r] - m) * 1.44269504f);
        sT1[r] = p; rs += p;
      }
      rs += __shfl_xor(rs, 32);
      lsum += rs;
      // ---- P -> bf16 A-frags in-register (cvt_pk + shfl_xor 32)
      unsigned cA0[4], cB0[4], cA1[4], cB1[4];
#pragma unroll
      for (int g = 0; g < 4; ++g) {
        cA0[g] = cvtpk(sT0[4 * g], sT0[4 * g + 1]);
        cB0[g] = cvtpk(sT0[4 * g + 2], sT0[4 * g + 3]);
        cA1[g] = cvtpk(sT1[4 * g], sT1[4 * g + 1]);
        cB1[g] = cvtpk(sT1[4 * g + 2], sT1[4 * g + 3]);
      }
      short8 pa[4];
#define PAK(kc2_, A_, B_, dst_) do {                                            \
        unsigned sA = hi ? A_[2*(kc2_)]   : A_[2*(kc2_)+1];                     \
        unsigned sB = hi ? B_[2*(kc2_)]   : B_[2*(kc2_)+1];                     \
        unsigned rA = (unsigned)__shfl_xor((int)sA, 32);                        \
        unsigned rB = (unsigned)__shfl_xor((int)sB, 32);                        \
        unsigned kA = hi ? A_[2*(kc2_)+1] : A_[2*(kc2_)];                       \
        unsigned kB = hi ? B_[2*(kc2_)+1] : B_[2*(kc2_)];                       \
        PU pu; pu.u = (uint4v){ hi ? rA : kA, hi ? rB : kB,                     \
                                hi ? kA : rA, hi ? kB : rB };                   \
        dst_ = pu.s;                                                            \
      } while (0)
      PAK(0, cA0, cB0, pa[0]);
      PAK(1, cA0, cB0, pa[1]);
      PAK(0, cA1, cB1, pa[2]);
      PAK(1, cA1, cB1, pa[3]);
#undef PAK
      // ---- PV
      __builtin_amdgcn_s_setprio(1);
#pragma unroll
      for (int kc = 0; kc < 4; ++kc) {
        short8 v0 = *(const short8*)&Vs[cur][(kc * 64 + l) * 8];
        short8 v1 = *(const short8*)&Vs[cur][((4 + kc) * 64 + l) * 8];
        o0 = mfma32(pa[kc], v0, o0);
        o1 = mfma32(pa[kc], v1, o1);
      }
      __builtin_amdgcn_s_setprio(0);
    }
    asm volatile("s_waitcnt lgkmcnt(0)" ::: "memory");
    __builtin_amdgcn_s_barrier();
  }
#undef STAGE

  float inv = 1.0f / lsum;
#pragma unroll
  for (int r = 0; r < 16; ++r) {
    int row = (r & 3) + 8 * (r >> 2) + 4 * hi;
    float fo = __shfl(inv, row);
    int qr = qw + row;
    long base = ((long)(b * 2048 + qr)) * 1024 + h * 64;
    Oh[base + ql]      = f2b(o0[r] * fo);
    Oh[base + 32 + ql] = f2b(o1[r] * fo);
  }
}

// ---------------------------------------------------------------- launch
extern "C" void kernel_launch(void* const* d_in, const int* in_sizes, int n_in,
                              void* d_out, int out_size, void* d_ws, size_t ws_size,
                              hipStream_t stream) {
  const float* x  = (const float*)d_in[0];
  const float* wq = (const float*)d_in[1];
  const float* wk = (const float*)d_in[2];
  const float* wv = (const float*)d_in[3];
  const float* wo = (const float*)d_in[4];
  const int* tok  = (const int*)d_in[5];

  short* wsp  = (short*)d_ws;
  short* xb   = wsp;
  short* wqkv = xb + 4194304;
  short* wob  = wqkv + 3145728;
  short* qkv  = wob + 1048576;
  short* qh   = qkv + 12582912;
  short* kh   = qh + 4194304;
  short* vt   = kh + 4194304;
  short* oh   = vt + 4194304;

  (void)in_sizes; (void)n_in; (void)out_size; (void)ws_size;

  cvt_all<<<8192, 256, 0, stream>>>(x, wq, wk, wv, wo, xb, wqkv, wob);
  gemm_bt<1><<<dim3(256, 3), 256, 0, stream>>>(xb, wqkv, qkv, 4096, 1024, 1024,
                                               1048576L, 4194304L);
  rope_split<<<4096, 256, 0, stream>>>(qkv, tok, qh, kh);
  vtrans<<<dim3(32, 32), 256, 0, stream>>>(qkv + 8388608, vt);
  attn_fwd<<<dim3(16, 32), 256, 0, stream>>>(qh, kh, vt, oh);
  gemm_bt<0><<<dim3(256, 1), 256, 0, stream>>>(oh, wob, d_out, 4096, 1024, 1024,
                                               0L, 0L);
}

// Round 3
// 137.808 us; speedup vs baseline: 1.5552x; 1.1371x over previous
//
#include <hip/hip_runtime.h>
#include <hip/hip_bf16.h>
#include <stdint.h>

// Problem constants
#define SEQL   2048
#define NBATCH 2
#define BSZ    4096   // NBATCH*SEQL
#define DMODEL 1024
#define NH     16
#define DK     64
#define NBH    32     // NBATCH*NH
#define NCHUNK_TOT 40 // sum over qi of ceil((2qi+2)/8)

typedef __attribute__((ext_vector_type(8)))  short short8;
typedef __attribute__((ext_vector_type(4)))  short shortx4;
typedef __attribute__((ext_vector_type(4)))  float f32x4;
typedef __attribute__((ext_vector_type(16))) float f32x16;
typedef __attribute__((ext_vector_type(4)))  unsigned uint4v;
union PU { uint4v u; short8 s; };

__device__ __forceinline__ short f2b(float f) {   // f32 -> bf16 (RNE)
  unsigned u = __float_as_uint(f);
  u = (u + 0x7FFF + ((u >> 16) & 1)) >> 16;
  return (short)u;
}
__device__ __forceinline__ float b2f(short s) {
  return __uint_as_float(((unsigned)(unsigned short)s) << 16);
}
__device__ __forceinline__ unsigned cvtpk(float lo, float hi) {
  unsigned r;
  asm("v_cvt_pk_bf16_f32 %0, %1, %2" : "=v"(r) : "v"(lo), "v"(hi));
  return r;
}

// async global->LDS, 16B per lane. LDS dest = wave-uniform base + lane*16.
__device__ __forceinline__ void g2l16(const void* g, void* l) {
  __builtin_amdgcn_global_load_lds(
      (__attribute__((address_space(1))) void*)(uintptr_t)g,
      (__attribute__((address_space(3))) void*)l, 16, 0, 0);
}

__device__ __forceinline__ f32x4 mfma16(short8 a, short8 b, f32x4 c) {
  return __builtin_amdgcn_mfma_f32_16x16x32_bf16(a, b, c, 0, 0, 0);
}
__device__ __forceinline__ f32x16 mfma32(short8 a, short8 b, f32x16 c) {
  return __builtin_amdgcn_mfma_f32_32x32x16_bf16(a, b, c, 0, 0, 0);
}

// ---------------------------------------------------------------- cvt f32->bf16
__global__ void cvt_all(const float* __restrict__ x,  const float* __restrict__ wq,
                        const float* __restrict__ wk, const float* __restrict__ wv,
                        const float* __restrict__ wo, short* __restrict__ xb,
                        short* __restrict__ wqkv, short* __restrict__ wob) {
  long idx = ((long)blockIdx.x * 256 + threadIdx.x) * 4;
  const float* s; short* d; long off;
  if (idx < 4194304L)      { s = x;  d = xb;             off = idx; }
  else if (idx < 5242880L) { s = wq; d = wqkv;           off = idx - 4194304L; }
  else if (idx < 6291456L) { s = wk; d = wqkv + 1048576; off = idx - 5242880L; }
  else if (idx < 7340032L) { s = wv; d = wqkv + 2097152; off = idx - 6291456L; }
  else                     { s = wo; d = wob;            off = idx - 7340032L; }
  float4 v = *(const float4*)(s + off);
  shortx4 r;
  r[0] = f2b(v.x); r[1] = f2b(v.y); r[2] = f2b(v.z); r[3] = f2b(v.w);
  *(shortx4*)(d + off) = r;
}

// ---------------------------------------------------------------- GEMM  C = A * B^T
template<int CBF16>
__global__ __launch_bounds__(256, 2)
void gemm_bt(const short* __restrict__ A, const short* __restrict__ B,
             void* __restrict__ Cv, int M, int N, int K,
             long bStride, long cStride) {
  __shared__ short As[4096];
  __shared__ short Bs[4096];
  B += (long)blockIdx.y * bStride;
  int nbn = N >> 7;
  int bm = blockIdx.x / nbn, bn = blockIdx.x % nbn;
  int tid = threadIdx.x, w = tid >> 6, l = tid & 63;
  int wm = w >> 1, wn = w & 1;
  int lr = l & 15, lg = l >> 4;
  int brow = bm << 7, bcol = bn << 7;

  const f32x4 fz = {0.f, 0.f, 0.f, 0.f};
  f32x4 acc[4][4];
#pragma unroll
  for (int xi = 0; xi < 4; ++xi)
#pragma unroll
    for (int yi = 0; yi < 4; ++yi) acc[xi][yi] = fz;

  for (int k0 = 0; k0 < K; k0 += 32) {
#pragma unroll
    for (int i = 0; i < 2; ++i) {
      int c = w * 2 + i;
      int chunk = c * 64 + l;
      int row = chunk >> 2, ch = chunk & 3;
      int gch = ch ^ ((row >> 1) & 3);
      g2l16(A + (long)(brow + row) * K + k0 + gch * 8, &As[c * 512]);
      g2l16(B + (long)(bcol + row) * K + k0 + gch * 8, &Bs[c * 512]);
    }
    __syncthreads();

    short8 af[4], bf[4];
#pragma unroll
    for (int xi = 0; xi < 4; ++xi) {
      int ar = wm * 64 + xi * 16 + lr;
      af[xi] = *(const short8*)&As[ar * 32 + ((lg ^ ((ar >> 1) & 3)) << 3)];
      int br = wn * 64 + xi * 16 + lr;
      bf[xi] = *(const short8*)&Bs[br * 32 + ((lg ^ ((br >> 1) & 3)) << 3)];
    }
#pragma unroll
    for (int xi = 0; xi < 4; ++xi)
#pragma unroll
      for (int yi = 0; yi < 4; ++yi)
        acc[xi][yi] = mfma16(af[xi], bf[yi], acc[xi][yi]);
    __syncthreads();
  }

  if (CBF16) {
    short* C = (short*)Cv + (long)blockIdx.y * cStride;
#pragma unroll
    for (int xi = 0; xi < 4; ++xi)
#pragma unroll
      for (int yi = 0; yi < 4; ++yi)
#pragma unroll
        for (int r = 0; r < 4; ++r) {
          int row = brow + wm * 64 + xi * 16 + lg * 4 + r;
          int col = bcol + wn * 64 + yi * 16 + lr;
          C[(long)row * N + col] = f2b(acc[xi][yi][r]);
        }
  } else {
    float* C = (float*)Cv;
#pragma unroll
    for (int xi = 0; xi < 4; ++xi)
#pragma unroll
      for (int yi = 0; yi < 4; ++yi)
#pragma unroll
        for (int r = 0; r < 4; ++r) {
          int row = brow + wm * 64 + xi * 16 + lg * 4 + r;
          int col = bcol + wn * 64 + yi * 16 + lr;
          C[(long)row * N + col] = acc[xi][yi][r];
        }
  }
}

// ---------------------------------------------------------------- RoPE + head split
__global__ void rope_split(const short* __restrict__ qkv, const int* __restrict__ tok,
                           short* __restrict__ Qh, short* __restrict__ Kh) {
  int t = blockIdx.x * 256 + threadIdx.x;
  int qd = t & 15, h = (t >> 4) & 15, bs = t >> 8;
  int b = bs >> 11, s = bs & 2047;
  float pos = (float)tok[s];
  long srcoff = (long)bs * 1024 + h * 64 + qd * 4;
  shortx4 q4 = *(const shortx4*)(qkv + srcoff);
  shortx4 k4 = *(const shortx4*)(qkv + 4194304L + srcoff);
  shortx4 qo, ko;
#pragma unroll
  for (int p = 0; p < 2; ++p) {
    int i = qd * 2 + p;
    float freq = exp2f(-(float)i * (13.287712379549449f / 32.0f));
    float ang = pos * freq;
    float sn, cs;
    sincosf(ang, &sn, &cs);
    float x1 = b2f(q4[p * 2]), x2 = b2f(q4[p * 2 + 1]);
    qo[p * 2]     = f2b((x1 * cs - x2 * sn) * 0.125f);
    qo[p * 2 + 1] = f2b((x1 * sn + x2 * cs) * 0.125f);
    float y1 = b2f(k4[p * 2]), y2 = b2f(k4[p * 2 + 1]);
    ko[p * 2]     = f2b(y1 * cs - y2 * sn);
    ko[p * 2 + 1] = f2b(y1 * sn + y2 * cs);
  }
  long outoff = ((long)(b * 16 + h) * 2048 + s) * 64 + qd * 4;
  *(shortx4*)(Qh + outoff) = qo;
  *(shortx4*)(Kh + outoff) = ko;
}

// ---------------------------------------------------------------- V transpose
__global__ void vtrans(const short* __restrict__ Vlin, short* __restrict__ Vt) {
  __shared__ short tile[64][72];
  int s0 = blockIdx.x * 64;
  int bh = blockIdx.y;
  int b = bh >> 4, h = bh & 15;
  int t = threadIdx.x;
  int r = t >> 2, c0 = (t & 3) * 16;
  const short* src = Vlin + ((long)(b * 2048 + s0 + r)) * 1024 + h * 64 + c0;
  *(short8*)&tile[r][c0]     = *(const short8*)src;
  *(short8*)&tile[r][c0 + 8] = *(const short8*)(src + 8);
  __syncthreads();
  int d = t >> 2, sc0 = (t & 3) * 16;
  short8 o0, o1;
#pragma unroll
  for (int j = 0; j < 8; ++j) { o0[j] = tile[sc0 + j][d]; o1[j] = tile[sc0 + 8 + j][d]; }
  short* dst = Vt + ((long)(bh * 64 + d)) * 2048 + s0 + sc0;
  *(short8*)dst       = o0;
  *(short8*)(dst + 8) = o1;
}

// ---------------------------------------------------------------- causal flash attention, split-KV
// grid (40, NBH): x' = 39-blockIdx.x enumerates (qi, chunk) with nchunks(qi) =
// (qi>>2)+1 (each chunk <= 8 kv-tiles of 64). 4 waves x 32 q-rows = 128 q/block.
// Writes unnormalized partials: poO bf16 [pid][128][64], pm/pl f32 [pid][128].
__global__ __launch_bounds__(256, 4)
void attn_fwd(const short* __restrict__ Qh, const short* __restrict__ Kh,
              const short* __restrict__ Vt, short* __restrict__ poO,
              float* __restrict__ pmb, float* __restrict__ plb) {
  __shared__ short Ks[2][4096];
  __shared__ short Vs[2][4096];
  int xr = 39 - blockIdx.x;                    // heavy-first
  int qi, c = xr, nc = 1;
  for (qi = 0; qi < 16; ++qi) { nc = (qi >> 2) + 1; if (c < nc) break; c -= nc; }
  int n = 2 * qi + 2;                          // kv-tiles for this q-tile
  int t0 = (c * n) / nc, t1 = ((c + 1) * n) / nc;
  int q0b = qi << 7;
  int bh = blockIdx.y;
  int tid = threadIdx.x, w = tid >> 6, l = tid & 63;
  int ql = l & 31, hi = l >> 5;
  const short* Qb = Qh + (long)bh * (2048 * 64);
  const short* Kb = Kh + (long)bh * (2048 * 64);
  const short* Vb = Vt + (long)bh * (64 * 2048);
  int qw = q0b + 32 * w;
  int qg = qw + ql;
  int pid = bh * NCHUNK_TOT + xr;

  // Q B-fragments: lane l holds Q[qw+ql][kc*16 + hi*8 + 0..8)
  short8 qf[4];
#pragma unroll
  for (int kc = 0; kc < 4; ++kc)
    qf[kc] = *(const short8*)(Qb + (long)qg * 64 + kc * 16 + hi * 8);

  f32x16 o0, o1;
#pragma unroll
  for (int r = 0; r < 16; ++r) { o0[r] = 0.f; o1[r] = 0.f; }
  float m = -1e30f, lsum = 0.f;

#define STAGE(t_, bufi_) do {                                                   \
    int s0_ = (t_) << 6;                                                        \
    _Pragma("unroll")                                                           \
    for (int i_ = 0; i_ < 2; ++i_) {                                            \
      int c_ = w + 4 * i_;                                                      \
      int g_ = c_ >> 2, cc_ = c_ & 3;                                           \
      g2l16(Kb + ((long)(s0_ + g_ * 32 + ql)) * 64 + cc_ * 16 + hi * 8,         \
            &Ks[bufi_][c_ * 512]);                                              \
      g2l16(Vb + ((long)(g_ * 32 + ql)) * 2048 + s0_ + cc_ * 16 + hi * 8,       \
            &Vs[bufi_][c_ * 512]);                                              \
    }                                                                           \
  } while (0)

  STAGE(t0, 0);

  for (int t = t0; t < t1; ++t) {
    int cur = (t - t0) & 1;
    if (t + 1 < t1) {
      STAGE(t + 1, cur ^ 1);
      asm volatile("s_waitcnt vmcnt(4)" ::: "memory");
    } else {
      asm volatile("s_waitcnt vmcnt(0)" ::: "memory");
    }
    __builtin_amdgcn_s_barrier();
    int s0 = t << 6;
    if (s0 <= qw + 31) {
      // ---- QK^T (swapped): lane owns q-col = ql
      f32x16 sT0, sT1;
#pragma unroll
      for (int r = 0; r < 16; ++r) { sT0[r] = 0.f; sT1[r] = 0.f; }
      __builtin_amdgcn_s_setprio(1);
#pragma unroll
      for (int kc = 0; kc < 4; ++kc) {
        short8 k0 = *(const short8*)&Ks[cur][(kc * 64 + l) * 8];
        short8 k1 = *(const short8*)&Ks[cur][((4 + kc) * 64 + l) * 8];
        sT0 = mfma32(k0, qf[kc], sT0);
        sT1 = mfma32(k1, qf[kc], sT1);
      }
      __builtin_amdgcn_s_setprio(0);
      // ---- causal mask
      if (s0 + 63 > qw) {
#pragma unroll
        for (int r = 0; r < 16; ++r) {
          int kvl = (r & 3) + 8 * (r >> 2) + 4 * hi;
          if (s0 + kvl > qg)      sT0[r] = -1e30f;
          if (s0 + 32 + kvl > qg) sT1[r] = -1e30f;
        }
      }
      // ---- online softmax (row = lane-local + partner via shfl_xor 32)
      float pmax = sT0[0];
#pragma unroll
      for (int r = 1; r < 16; ++r) pmax = fmaxf(pmax, sT0[r]);
#pragma unroll
      for (int r = 0; r < 16; ++r) pmax = fmaxf(pmax, sT1[r]);
      pmax = fmaxf(pmax, __shfl_xor(pmax, 32));
      if (__any(pmax > m + 8.0f)) {            // T13 defer-max
        float mn = fmaxf(m, pmax);
        float sf = exp2f((m - mn) * 1.44269504f);
        m = mn;
        lsum *= sf;
#pragma unroll
        for (int r = 0; r < 16; ++r) {
          int row = (r & 3) + 8 * (r >> 2) + 4 * hi;
          float fo = __shfl(sf, row);
          o0[r] *= fo; o1[r] *= fo;
        }
      }
      float rs = 0.f;
#pragma unroll
      for (int r = 0; r < 16; ++r) {
        float p = exp2f((sT0[r] - m) * 1.44269504f);
        sT0[r] = p; rs += p;
      }
#pragma unroll
      for (int r = 0; r < 16; ++r) {
        float p = exp2f((sT1[r] - m) * 1.44269504f);
        sT1[r] = p; rs += p;
      }
      rs += __shfl_xor(rs, 32);
      lsum += rs;
      // ---- P -> bf16 A-frags in-register (cvt_pk + shfl_xor 32)
      unsigned cA0[4], cB0[4], cA1[4], cB1[4];
#pragma unroll
      for (int g = 0; g < 4; ++g) {
        cA0[g] = cvtpk(sT0[4 * g], sT0[4 * g + 1]);
        cB0[g] = cvtpk(sT0[4 * g + 2], sT0[4 * g + 3]);
        cA1[g] = cvtpk(sT1[4 * g], sT1[4 * g + 1]);
        cB1[g] = cvtpk(sT1[4 * g + 2], sT1[4 * g + 3]);
      }
      short8 pa[4];
#define PAK(kc2_, A_, B_, dst_) do {                                            \
        unsigned sA = hi ? A_[2*(kc2_)]   : A_[2*(kc2_)+1];                     \
        unsigned sB = hi ? B_[2*(kc2_)]   : B_[2*(kc2_)+1];                     \
        unsigned rA = (unsigned)__shfl_xor((int)sA, 32);                        \
        unsigned rB = (unsigned)__shfl_xor((int)sB, 32);                        \
        unsigned kA = hi ? A_[2*(kc2_)+1] : A_[2*(kc2_)];                       \
        unsigned kB = hi ? B_[2*(kc2_)+1] : B_[2*(kc2_)];                       \
        PU pu; pu.u = (uint4v){ hi ? rA : kA, hi ? rB : kB,                     \
                                hi ? kA : rA, hi ? kB : rB };                   \
        dst_ = pu.s;                                                            \
      } while (0)
      PAK(0, cA0, cB0, pa[0]);
      PAK(1, cA0, cB0, pa[1]);
      PAK(0, cA1, cB1, pa[2]);
      PAK(1, cA1, cB1, pa[3]);
#undef PAK
      // ---- PV
      __builtin_amdgcn_s_setprio(1);
#pragma unroll
      for (int kc = 0; kc < 4; ++kc) {
        short8 v0 = *(const short8*)&Vs[cur][(kc * 64 + l) * 8];
        short8 v1 = *(const short8*)&Vs[cur][((4 + kc) * 64 + l) * 8];
        o0 = mfma32(pa[kc], v0, o0);
        o1 = mfma32(pa[kc], v1, o1);
      }
      __builtin_amdgcn_s_setprio(0);
    }
    asm volatile("s_waitcnt lgkmcnt(0)" ::: "memory");
    __builtin_amdgcn_s_barrier();
  }
#undef STAGE

  // ---- write unnormalized partials
  if (hi == 0) {
    pmb[pid * 128 + w * 32 + ql] = m;
    plb[pid * 128 + w * 32 + ql] = lsum;
  }
#pragma unroll
  for (int r = 0; r < 16; ++r) {
    int row = (r & 3) + 8 * (r >> 2) + 4 * hi;
    long basep = ((long)pid * 128 + w * 32 + row) * 64;
    poO[basep + ql]      = f2b(o0[r]);
    poO[basep + 32 + ql] = f2b(o1[r]);
  }
}

// ---------------------------------------------------------------- combine partials
// grid (64, NBH): qi = x>>2, 32 rows per block-slice; thread -> (row, 8 d-elems)
__global__ void attn_combine(const short* __restrict__ poO,
                             const float* __restrict__ pmb,
                             const float* __restrict__ plb,
                             short* __restrict__ Oh) {
  int x = blockIdx.x, bh = blockIdx.y;
  int qi = x >> 2, sub = x & 3;
  int t = threadIdx.x;
  int r = sub * 32 + (t >> 3);
  int d0 = (t & 7) * 8;
  int nc = (qi >> 2) + 1;
  int prefix = 0;
  for (int j = 0; j < qi; ++j) prefix += (j >> 2) + 1;
  int base = bh * NCHUNK_TOT + prefix;
  float M = -1e30f;
  for (int i = 0; i < nc; ++i)
    M = fmaxf(M, pmb[(base + i) * 128 + r]);
  float acc0 = 0, acc1 = 0, acc2 = 0, acc3 = 0, acc4 = 0, acc5 = 0, acc6 = 0, acc7 = 0;
  float den = 0.f;
  for (int i = 0; i < nc; ++i) {
    float wgt = exp2f((pmb[(base + i) * 128 + r] - M) * 1.44269504f);
    den += wgt * plb[(base + i) * 128 + r];
    short8 ov = *(const short8*)&poO[((long)(base + i) * 128 + r) * 64 + d0];
    acc0 += wgt * b2f(ov[0]); acc1 += wgt * b2f(ov[1]);
    acc2 += wgt * b2f(ov[2]); acc3 += wgt * b2f(ov[3]);
    acc4 += wgt * b2f(ov[4]); acc5 += wgt * b2f(ov[5]);
    acc6 += wgt * b2f(ov[6]); acc7 += wgt * b2f(ov[7]);
  }
  float inv = 1.0f / den;
  int b = bh >> 4, h = bh & 15;
  int s = qi * 128 + r;
  short8 out;
  out[0] = f2b(acc0 * inv); out[1] = f2b(acc1 * inv);
  out[2] = f2b(acc2 * inv); out[3] = f2b(acc3 * inv);
  out[4] = f2b(acc4 * inv); out[5] = f2b(acc5 * inv);
  out[6] = f2b(acc6 * inv); out[7] = f2b(acc7 * inv);
  *(short8*)&Oh[((long)(b * 2048 + s)) * 1024 + h * 64 + d0] = out;
}

// ---------------------------------------------------------------- launch
extern "C" void kernel_launch(void* const* d_in, const int* in_sizes, int n_in,
                              void* d_out, int out_size, void* d_ws, size_t ws_size,
                              hipStream_t stream) {
  const float* x  = (const float*)d_in[0];
  const float* wq = (const float*)d_in[1];
  const float* wk = (const float*)d_in[2];
  const float* wv = (const float*)d_in[3];
  const float* wo = (const float*)d_in[4];
  const int* tok  = (const int*)d_in[5];

  short* wsp  = (short*)d_ws;
  short* xb   = wsp;                    //  4M shorts
  short* wqkv = xb + 4194304;           //  3M
  short* wob  = wqkv + 3145728;         //  1M
  short* qkv  = wob + 1048576;          // 12M (Q | K | V, 4M each)
  short* qh   = qkv + 12582912;         //  4M
  short* kh   = qh + 4194304;           //  4M
  short* vt   = kh + 4194304;           //  4M
  short* oh   = vt + 4194304;           //  4M

  // attention partials overlay regions dead during attn:
  short* poO = qkv;                     // 1280*128*64 bf16 = 10.5M shorts (< 12M)
  float* pmb = (float*)xb;              // 1280*128 f32
  float* plb = pmb + NCHUNK_TOT * NBH * 128;

  (void)in_sizes; (void)n_in; (void)out_size; (void)ws_size;

  cvt_all<<<8192, 256, 0, stream>>>(x, wq, wk, wv, wo, xb, wqkv, wob);
  gemm_bt<1><<<dim3(256, 3), 256, 0, stream>>>(xb, wqkv, qkv, 4096, 1024, 1024,
                                               1048576L, 4194304L);
  rope_split<<<4096, 256, 0, stream>>>(qkv, tok, qh, kh);
  vtrans<<<dim3(32, 32), 256, 0, stream>>>(qkv + 8388608, vt);
  attn_fwd<<<dim3(NCHUNK_TOT, 32), 256, 0, stream>>>(qh, kh, vt, poO, pmb, plb);
  attn_combine<<<dim3(64, 32), 256, 0, stream>>>(poO, pmb, plb, oh);
  gemm_bt<0><<<dim3(256, 1), 256, 0, stream>>>(oh, wob, d_out, 4096, 1024, 1024,
                                               0L, 0L);
}

// Round 4
// 130.508 us; speedup vs baseline: 1.6422x; 1.0559x over previous
//
#include <hip/hip_runtime.h>
#include <hip/hip_bf16.h>
#include <stdint.h>

// Problem constants
#define SEQL   2048
#define NBATCH 2
#define BSZ    4096   // NBATCH*SEQL
#define DMODEL 1024
#define NH     16
#define DK     64
#define NBH    32     // NBATCH*NH
#define NCHUNK_TOT 40 // sum over qi of ceil((2qi+2)/8)

typedef __attribute__((ext_vector_type(8)))  short short8;
typedef __attribute__((ext_vector_type(4)))  short shortx4;
typedef __attribute__((ext_vector_type(4)))  float f32x4;
typedef __attribute__((ext_vector_type(16))) float f32x16;
typedef __attribute__((ext_vector_type(4)))  unsigned uint4v;
union PU { uint4v u; short8 s; };

__device__ __forceinline__ short f2b(float f) {   // f32 -> bf16 (RNE)
  unsigned u = __float_as_uint(f);
  u = (u + 0x7FFF + ((u >> 16) & 1)) >> 16;
  return (short)u;
}
__device__ __forceinline__ float b2f(short s) {
  return __uint_as_float(((unsigned)(unsigned short)s) << 16);
}
__device__ __forceinline__ unsigned cvtpk(float lo, float hi) {
  unsigned r;
  asm("v_cvt_pk_bf16_f32 %0, %1, %2" : "=v"(r) : "v"(lo), "v"(hi));
  return r;
}
// swap a's upper-32-lane half with b's lower-32-lane half (in place)
#define PLSWAP(a_, b_) asm("v_permlane32_swap_b32 %0, %1" : "+v"(a_), "+v"(b_))

// async global->LDS, 16B per lane. LDS dest = wave-uniform base + lane*16.
__device__ __forceinline__ void g2l16(const void* g, void* l) {
  __builtin_amdgcn_global_load_lds(
      (__attribute__((address_space(1))) void*)(uintptr_t)g,
      (__attribute__((address_space(3))) void*)l, 16, 0, 0);
}

__device__ __forceinline__ f32x4 mfma16(short8 a, short8 b, f32x4 c) {
  return __builtin_amdgcn_mfma_f32_16x16x32_bf16(a, b, c, 0, 0, 0);
}
__device__ __forceinline__ f32x16 mfma32(short8 a, short8 b, f32x16 c) {
  return __builtin_amdgcn_mfma_f32_32x32x16_bf16(a, b, c, 0, 0, 0);
}

// ---------------------------------------------------------------- cvt f32->bf16
__global__ void cvt_all(const float* __restrict__ x,  const float* __restrict__ wq,
                        const float* __restrict__ wk, const float* __restrict__ wv,
                        const float* __restrict__ wo, short* __restrict__ xb,
                        short* __restrict__ wqkv, short* __restrict__ wob) {
  long idx = ((long)blockIdx.x * 256 + threadIdx.x) * 4;
  const float* s; short* d; long off;
  if (idx < 4194304L)      { s = x;  d = xb;             off = idx; }
  else if (idx < 5242880L) { s = wq; d = wqkv;           off = idx - 4194304L; }
  else if (idx < 6291456L) { s = wk; d = wqkv + 1048576; off = idx - 5242880L; }
  else if (idx < 7340032L) { s = wv; d = wqkv + 2097152; off = idx - 6291456L; }
  else                     { s = wo; d = wob;            off = idx - 7340032L; }
  float4 v = *(const float4*)(s + off);
  shortx4 r;
  r[0] = f2b(v.x); r[1] = f2b(v.y); r[2] = f2b(v.z); r[3] = f2b(v.w);
  *(shortx4*)(d + off) = r;
}

// ---------------------------------------------------------------- GEMM  C = A * B^T
template<int CBF16>
__global__ __launch_bounds__(256, 2)
void gemm_bt(const short* __restrict__ A, const short* __restrict__ B,
             void* __restrict__ Cv, int M, int N, int K,
             long bStride, long cStride) {
  __shared__ short As[4096];
  __shared__ short Bs[4096];
  B += (long)blockIdx.y * bStride;
  int nbn = N >> 7;
  int bm = blockIdx.x / nbn, bn = blockIdx.x % nbn;
  int tid = threadIdx.x, w = tid >> 6, l = tid & 63;
  int wm = w >> 1, wn = w & 1;
  int lr = l & 15, lg = l >> 4;
  int brow = bm << 7, bcol = bn << 7;

  const f32x4 fz = {0.f, 0.f, 0.f, 0.f};
  f32x4 acc[4][4];
#pragma unroll
  for (int xi = 0; xi < 4; ++xi)
#pragma unroll
    for (int yi = 0; yi < 4; ++yi) acc[xi][yi] = fz;

  for (int k0 = 0; k0 < K; k0 += 32) {
#pragma unroll
    for (int i = 0; i < 2; ++i) {
      int c = w * 2 + i;
      int chunk = c * 64 + l;
      int row = chunk >> 2, ch = chunk & 3;
      int gch = ch ^ ((row >> 1) & 3);
      g2l16(A + (long)(brow + row) * K + k0 + gch * 8, &As[c * 512]);
      g2l16(B + (long)(bcol + row) * K + k0 + gch * 8, &Bs[c * 512]);
    }
    __syncthreads();

    short8 af[4], bf[4];
#pragma unroll
    for (int xi = 0; xi < 4; ++xi) {
      int ar = wm * 64 + xi * 16 + lr;
      af[xi] = *(const short8*)&As[ar * 32 + ((lg ^ ((ar >> 1) & 3)) << 3)];
      int br = wn * 64 + xi * 16 + lr;
      bf[xi] = *(const short8*)&Bs[br * 32 + ((lg ^ ((br >> 1) & 3)) << 3)];
    }
#pragma unroll
    for (int xi = 0; xi < 4; ++xi)
#pragma unroll
      for (int yi = 0; yi < 4; ++yi)
        acc[xi][yi] = mfma16(af[xi], bf[yi], acc[xi][yi]);
    __syncthreads();
  }

  if (CBF16) {
    short* C = (short*)Cv + (long)blockIdx.y * cStride;
#pragma unroll
    for (int xi = 0; xi < 4; ++xi)
#pragma unroll
      for (int yi = 0; yi < 4; ++yi)
#pragma unroll
        for (int r = 0; r < 4; ++r) {
          int row = brow + wm * 64 + xi * 16 + lg * 4 + r;
          int col = bcol + wn * 64 + yi * 16 + lr;
          C[(long)row * N + col] = f2b(acc[xi][yi][r]);
        }
  } else {
    float* C = (float*)Cv;
#pragma unroll
    for (int xi = 0; xi < 4; ++xi)
#pragma unroll
      for (int yi = 0; yi < 4; ++yi)
#pragma unroll
        for (int r = 0; r < 4; ++r) {
          int row = brow + wm * 64 + xi * 16 + lg * 4 + r;
          int col = bcol + wn * 64 + yi * 16 + lr;
          C[(long)row * N + col] = acc[xi][yi][r];
        }
  }
}

// ---------------------------------------------------------------- RoPE + head split
// Q gets *0.125*log2e so QK^T scores land in the log2 domain (exp2-direct).
__global__ void rope_split(const short* __restrict__ qkv, const int* __restrict__ tok,
                           short* __restrict__ Qh, short* __restrict__ Kh) {
  int t = blockIdx.x * 256 + threadIdx.x;
  int qd = t & 15, h = (t >> 4) & 15, bs = t >> 8;
  int b = bs >> 11, s = bs & 2047;
  float pos = (float)tok[s];
  long srcoff = (long)bs * 1024 + h * 64 + qd * 4;
  shortx4 q4 = *(const shortx4*)(qkv + srcoff);
  shortx4 k4 = *(const shortx4*)(qkv + 4194304L + srcoff);
  shortx4 qo, ko;
#pragma unroll
  for (int p = 0; p < 2; ++p) {
    int i = qd * 2 + p;
    float freq = exp2f(-(float)i * (13.287712379549449f / 32.0f));
    float ang = pos * freq;
    float sn, cs;
    sincosf(ang, &sn, &cs);
    const float QS = 0.125f * 1.44269504f;
    float x1 = b2f(q4[p * 2]), x2 = b2f(q4[p * 2 + 1]);
    qo[p * 2]     = f2b((x1 * cs - x2 * sn) * QS);
    qo[p * 2 + 1] = f2b((x1 * sn + x2 * cs) * QS);
    float y1 = b2f(k4[p * 2]), y2 = b2f(k4[p * 2 + 1]);
    ko[p * 2]     = f2b(y1 * cs - y2 * sn);
    ko[p * 2 + 1] = f2b(y1 * sn + y2 * cs);
  }
  long outoff = ((long)(b * 16 + h) * 2048 + s) * 64 + qd * 4;
  *(shortx4*)(Qh + outoff) = qo;
  *(shortx4*)(Kh + outoff) = ko;
}

// ---------------------------------------------------------------- V transpose
__global__ void vtrans(const short* __restrict__ Vlin, short* __restrict__ Vt) {
  __shared__ short tile[64][72];
  int s0 = blockIdx.x * 64;
  int bh = blockIdx.y;
  int b = bh >> 4, h = bh & 15;
  int t = threadIdx.x;
  int r = t >> 2, c0 = (t & 3) * 16;
  const short* src = Vlin + ((long)(b * 2048 + s0 + r)) * 1024 + h * 64 + c0;
  *(short8*)&tile[r][c0]     = *(const short8*)src;
  *(short8*)&tile[r][c0 + 8] = *(const short8*)(src + 8);
  __syncthreads();
  int d = t >> 2, sc0 = (t & 3) * 16;
  short8 o0, o1;
#pragma unroll
  for (int j = 0; j < 8; ++j) { o0[j] = tile[sc0 + j][d]; o1[j] = tile[sc0 + 8 + j][d]; }
  short* dst = Vt + ((long)(bh * 64 + d)) * 2048 + s0 + sc0;
  *(short8*)dst       = o0;
  *(short8*)(dst + 8) = o1;
}

// ---------------------------------------------------------------- causal flash attention, split-KV
// grid (NBH, 40): blockIdx.x = bh so XCD = id%8 = bh%8 (L2-locality, T1);
// y enumerates (qi, chunk) heavy-first. 4 waves x 32 q-rows = 128 q/block.
// 3-deep LDS pipeline (48KB), counted vmcnt(8). Scores in log2 domain.
__global__ __launch_bounds__(256, 3)
void attn_fwd(const short* __restrict__ Qh, const short* __restrict__ Kh,
              const short* __restrict__ Vt, short* __restrict__ poO,
              float* __restrict__ pmb, float* __restrict__ plb) {
  __shared__ short Ks[3][4096];
  __shared__ short Vs[3][4096];
  int bh = blockIdx.x;
  int xr = 39 - blockIdx.y;                    // y=0 -> heaviest chunk
  int qi, c = xr, nc = 1;
  for (qi = 0; qi < 16; ++qi) { nc = (qi >> 2) + 1; if (c < nc) break; c -= nc; }
  int n = 2 * qi + 2;                          // kv-tiles for this q-tile
  int t0 = (c * n) / nc, t1 = ((c + 1) * n) / nc;
  int q0b = qi << 7;
  int tid = threadIdx.x, w = tid >> 6, l = tid & 63;
  int ql = l & 31, hi = l >> 5;
  const short* Qb = Qh + (long)bh * (2048 * 64);
  const short* Kb = Kh + (long)bh * (2048 * 64);
  const short* Vb = Vt + (long)bh * (64 * 2048);
  int qw = q0b + 32 * w;
  int qg = qw + ql;
  int pid = bh * NCHUNK_TOT + xr;

  short8 qf[4];
#pragma unroll
  for (int kc = 0; kc < 4; ++kc)
    qf[kc] = *(const short8*)(Qb + (long)qg * 64 + kc * 16 + hi * 8);

  f32x16 o0, o1;
#pragma unroll
  for (int r = 0; r < 16; ++r) { o0[r] = 0.f; o1[r] = 0.f; }
  float m = -1e30f, lsum = 0.f;

#define STAGE(t_, bufi_) do {                                                   \
    int s0_ = (t_) << 6;                                                        \
    _Pragma("unroll")                                                           \
    for (int i_ = 0; i_ < 2; ++i_) {                                            \
      int c_ = w + 4 * i_;                                                      \
      int g_ = c_ >> 2, cc_ = c_ & 3;                                           \
      g2l16(Kb + ((long)(s0_ + g_ * 32 + ql)) * 64 + cc_ * 16 + hi * 8,         \
            &Ks[bufi_][c_ * 512]);                                              \
      g2l16(Vb + ((long)(g_ * 32 + ql)) * 2048 + s0_ + cc_ * 16 + hi * 8,       \
            &Vs[bufi_][c_ * 512]);                                              \
    }                                                                           \
  } while (0)

  STAGE(t0, 0);
  if (t0 + 1 < t1) STAGE(t0 + 1, 1);
  int cur = 0;

  for (int t = t0; t < t1; ++t) {
    if (t + 2 < t1) {
      int nb = cur + 2; if (nb >= 3) nb -= 3;
      STAGE(t + 2, nb);
      asm volatile("s_waitcnt vmcnt(8)" ::: "memory");
    } else if (t + 1 < t1) {
      asm volatile("s_waitcnt vmcnt(4)" ::: "memory");
    } else {
      asm volatile("s_waitcnt vmcnt(0)" ::: "memory");
    }
    __builtin_amdgcn_s_barrier();
    int s0 = t << 6;
    if (s0 <= qw + 31) {
      bool upper = (s0 + 32 <= qw + 31);       // any survivors in kv 32..63?
      // ---- QK^T (swapped): lane owns q-col = ql; scores already *log2e
      f32x16 sT0, sT1;
#pragma unroll
      for (int r = 0; r < 16; ++r) { sT0[r] = 0.f; sT1[r] = 0.f; }
      __builtin_amdgcn_s_setprio(1);
#pragma unroll
      for (int kc = 0; kc < 4; ++kc) {
        short8 k0 = *(const short8*)&Ks[cur][(kc * 64 + l) * 8];
        sT0 = mfma32(k0, qf[kc], sT0);
      }
      if (upper) {
#pragma unroll
        for (int kc = 0; kc < 4; ++kc) {
          short8 k1 = *(const short8*)&Ks[cur][((4 + kc) * 64 + l) * 8];
          sT1 = mfma32(k1, qf[kc], sT1);
        }
      }
      __builtin_amdgcn_s_setprio(0);
      // ---- causal mask (diagonal region only)
      if (s0 + 63 > qw) {
#pragma unroll
        for (int r = 0; r < 16; ++r) {
          int kvl = (r & 3) + 8 * (r >> 2) + 4 * hi;
          if (s0 + kvl > qg) sT0[r] = -1e30f;
        }
        if (upper) {
#pragma unroll
          for (int r = 0; r < 16; ++r) {
            int kvl = (r & 3) + 8 * (r >> 2) + 4 * hi;
            if (s0 + 32 + kvl > qg) sT1[r] = -1e30f;
          }
        }
      }
      // ---- online softmax (log2 domain)
      float pmax = sT0[0];
#pragma unroll
      for (int r = 1; r < 16; ++r) pmax = fmaxf(pmax, sT0[r]);
      if (upper) {
#pragma unroll
        for (int r = 0; r < 16; ++r) pmax = fmaxf(pmax, sT1[r]);
      }
      pmax = fmaxf(pmax, __shfl_xor(pmax, 32));
      if (__any(pmax > m + 11.5416f)) {        // T13 defer-max (8 nats)
        float mn = fmaxf(m, pmax);
        float sf = exp2f(m - mn);
        m = mn;
        lsum *= sf;
#pragma unroll
        for (int r = 0; r < 16; ++r) {
          int row = (r & 3) + 8 * (r >> 2) + 4 * hi;
          float fo = __shfl(sf, row);
          o0[r] *= fo; o1[r] *= fo;
        }
      }
      float rs = 0.f;
#pragma unroll
      for (int r = 0; r < 16; ++r) {
        float p = exp2f(sT0[r] - m);
        sT0[r] = p; rs += p;
      }
      if (upper) {
#pragma unroll
        for (int r = 0; r < 16; ++r) {
          float p = exp2f(sT1[r] - m);
          sT1[r] = p; rs += p;
        }
      }
      rs += __shfl_xor(rs, 32);
      lsum += rs;
      // ---- P -> bf16 A-frags: cvt_pk + permlane32_swap (T12)
      short8 pa[4];
      {
        unsigned cA[4], cB[4];
#pragma unroll
        for (int g = 0; g < 4; ++g) {
          cA[g] = cvtpk(sT0[4 * g], sT0[4 * g + 1]);
          cB[g] = cvtpk(sT0[4 * g + 2], sT0[4 * g + 3]);
        }
        PLSWAP(cA[0], cA[1]); PLSWAP(cB[0], cB[1]);
        PLSWAP(cA[2], cA[3]); PLSWAP(cB[2], cB[3]);
        PU p0; p0.u = (uint4v){cA[0], cB[0], cA[1], cB[1]}; pa[0] = p0.s;
        PU p1; p1.u = (uint4v){cA[2], cB[2], cA[3], cB[3]}; pa[1] = p1.s;
      }
      if (upper) {
        unsigned cA[4], cB[4];
#pragma unroll
        for (int g = 0; g < 4; ++g) {
          cA[g] = cvtpk(sT1[4 * g], sT1[4 * g + 1]);
          cB[g] = cvtpk(sT1[4 * g + 2], sT1[4 * g + 3]);
        }
        PLSWAP(cA[0], cA[1]); PLSWAP(cB[0], cB[1]);
        PLSWAP(cA[2], cA[3]); PLSWAP(cB[2], cB[3]);
        PU p2; p2.u = (uint4v){cA[0], cB[0], cA[1], cB[1]}; pa[2] = p2.s;
        PU p3; p3.u = (uint4v){cA[2], cB[2], cA[3], cB[3]}; pa[3] = p3.s;
      }
      // ---- PV
      __builtin_amdgcn_s_setprio(1);
#pragma unroll
      for (int kc = 0; kc < 2; ++kc) {
        short8 v0 = *(const short8*)&Vs[cur][(kc * 64 + l) * 8];
        short8 v1 = *(const short8*)&Vs[cur][((4 + kc) * 64 + l) * 8];
        o0 = mfma32(pa[kc], v0, o0);
        o1 = mfma32(pa[kc], v1, o1);
      }
      if (upper) {
#pragma unroll
        for (int kc = 2; kc < 4; ++kc) {
          short8 v0 = *(const short8*)&Vs[cur][(kc * 64 + l) * 8];
          short8 v1 = *(const short8*)&Vs[cur][((4 + kc) * 64 + l) * 8];
          o0 = mfma32(pa[kc], v0, o0);
          o1 = mfma32(pa[kc], v1, o1);
        }
      }
      __builtin_amdgcn_s_setprio(0);
    }
    asm volatile("s_waitcnt lgkmcnt(0)" ::: "memory");
    __builtin_amdgcn_s_barrier();
    ++cur; if (cur >= 3) cur -= 3;
  }
#undef STAGE

  // ---- write unnormalized partials (m in log2 units)
  if (hi == 0) {
    pmb[pid * 128 + w * 32 + ql] = m;
    plb[pid * 128 + w * 32 + ql] = lsum;
  }
#pragma unroll
  for (int r = 0; r < 16; ++r) {
    int row = (r & 3) + 8 * (r >> 2) + 4 * hi;
    long basep = ((long)pid * 128 + w * 32 + row) * 64;
    poO[basep + ql]      = f2b(o0[r]);
    poO[basep + 32 + ql] = f2b(o1[r]);
  }
}

// ---------------------------------------------------------------- combine partials
__global__ void attn_combine(const short* __restrict__ poO,
                             const float* __restrict__ pmb,
                             const float* __restrict__ plb,
                             short* __restrict__ Oh) {
  int x = blockIdx.x, bh = blockIdx.y;
  int qi = x >> 2, sub = x & 3;
  int t = threadIdx.x;
  int r = sub * 32 + (t >> 3);
  int d0 = (t & 7) * 8;
  int nc = (qi >> 2) + 1;
  int prefix = 0;
  for (int j = 0; j < qi; ++j) prefix += (j >> 2) + 1;
  int base = bh * NCHUNK_TOT + prefix;
  float M = -1e30f;
  for (int i = 0; i < nc; ++i)
    M = fmaxf(M, pmb[(base + i) * 128 + r]);
  float acc0 = 0, acc1 = 0, acc2 = 0, acc3 = 0, acc4 = 0, acc5 = 0, acc6 = 0, acc7 = 0;
  float den = 0.f;
  for (int i = 0; i < nc; ++i) {
    float wgt = exp2f(pmb[(base + i) * 128 + r] - M);   // log2 domain
    den += wgt * plb[(base + i) * 128 + r];
    short8 ov = *(const short8*)&poO[((long)(base + i) * 128 + r) * 64 + d0];
    acc0 += wgt * b2f(ov[0]); acc1 += wgt * b2f(ov[1]);
    acc2 += wgt * b2f(ov[2]); acc3 += wgt * b2f(ov[3]);
    acc4 += wgt * b2f(ov[4]); acc5 += wgt * b2f(ov[5]);
    acc6 += wgt * b2f(ov[6]); acc7 += wgt * b2f(ov[7]);
  }
  float inv = 1.0f / den;
  int b = bh >> 4, h = bh & 15;
  int s = qi * 128 + r;
  short8 out;
  out[0] = f2b(acc0 * inv); out[1] = f2b(acc1 * inv);
  out[2] = f2b(acc2 * inv); out[3] = f2b(acc3 * inv);
  out[4] = f2b(acc4 * inv); out[5] = f2b(acc5 * inv);
  out[6] = f2b(acc6 * inv); out[7] = f2b(acc7 * inv);
  *(short8*)&Oh[((long)(b * 2048 + s)) * 1024 + h * 64 + d0] = out;
}

// ---------------------------------------------------------------- launch
extern "C" void kernel_launch(void* const* d_in, const int* in_sizes, int n_in,
                              void* d_out, int out_size, void* d_ws, size_t ws_size,
                              hipStream_t stream) {
  const float* x  = (const float*)d_in[0];
  const float* wq = (const float*)d_in[1];
  const float* wk = (const float*)d_in[2];
  const float* wv = (const float*)d_in[3];
  const float* wo = (const float*)d_in[4];
  const int* tok  = (const int*)d_in[5];

  short* wsp  = (short*)d_ws;
  short* xb   = wsp;                    //  4M shorts
  short* wqkv = xb + 4194304;           //  3M
  short* wob  = wqkv + 3145728;         //  1M
  short* qkv  = wob + 1048576;          // 12M (Q | K | V, 4M each)
  short* qh   = qkv + 12582912;         //  4M
  short* kh   = qh + 4194304;           //  4M
  short* vt   = kh + 4194304;           //  4M
  short* oh   = vt + 4194304;           //  4M

  // attention partials overlay regions dead during attn:
  short* poO = qkv;                     // 1280*128*64 bf16 = 10.5M shorts (< 12M)
  float* pmb = (float*)xb;              // 1280*128 f32
  float* plb = pmb + NCHUNK_TOT * NBH * 128;

  (void)in_sizes; (void)n_in; (void)out_size; (void)ws_size;

  cvt_all<<<8192, 256, 0, stream>>>(x, wq, wk, wv, wo, xb, wqkv, wob);
  gemm_bt<1><<<dim3(256, 3), 256, 0, stream>>>(xb, wqkv, qkv, 4096, 1024, 1024,
                                               1048576L, 4194304L);
  rope_split<<<4096, 256, 0, stream>>>(qkv, tok, qh, kh);
  vtrans<<<dim3(32, 32), 256, 0, stream>>>(qkv + 8388608, vt);
  attn_fwd<<<dim3(32, NCHUNK_TOT), 256, 0, stream>>>(qh, kh, vt, poO, pmb, plb);
  attn_combine<<<dim3(64, 32), 256, 0, stream>>>(poO, pmb, plb, oh);
  gemm_bt<0><<<dim3(256, 1), 256, 0, stream>>>(oh, wob, d_out, 4096, 1024, 1024,
                                               0L, 0L);
}